// Round 16
// baseline (60.992 us; speedup 1.0000x reference)
//
#include <hip/hip_runtime.h>
#include <hip/hip_bf16.h>

typedef __attribute__((ext_vector_type(4))) float  f32x4;
typedef __attribute__((ext_vector_type(8))) __bf16 bf16x8;
typedef unsigned int uint_t;

#define S_LEN  4096
#define D_DIM  64
#define NT64   64       /* 64-seq tiles per batch */
#define PITEM  8704     /* bf16 units per partial: O[128][64] bf16 + m[128],l[128] f32 */
#define IPB    140      /* multi-chunk partial items per batch */

typedef __attribute__((address_space(3))) uint_t*       lds_u32p;
typedef const __attribute__((address_space(1))) uint_t* gbl_u32p;

// ---------------- pre-pass: Q bf16 (scaled) row-major; K,V -> swizzled 64x64 tiles ----------------
// Tile chunk layout (16B units): chunk c_lin = row*8 + col16 stored at c_lin ^ (row&7).
// V tiles are transposed (rows = d, cols = kv).
__global__ __launch_bounds__(256) void prep_kernel(
    const float* __restrict__ Qg, const float* __restrict__ Kg,
    const float* __restrict__ Vg,
    __bf16* __restrict__ Qbf, __bf16* __restrict__ Ktil, __bf16* __restrict__ Vtil)
{
    __shared__ __bf16 vt_l[64][72];

    const float SCALE = 0.125f * 1.44269504088896340736f; // 1/sqrt(64) * log2(e)
    const int tid   = threadIdx.x;
    const int bid   = blockIdx.x;
    const int batch = bid >> 6;
    const int ti    = bid & 63;
    const int s0    = ti << 6;
    const size_t boff  = (size_t)batch * S_LEN * D_DIM;
    const size_t tbase = ((size_t)batch * NT64 + ti) * 4096;

    #pragma unroll
    for (int rep = 0; rep < 2; ++rep) {
        const int idx = rep * 256 + tid;   // 0..511 : 16B chunk id (r*8 + d8)
        const int r   = idx >> 3;
        const int d8  = idx & 7;
        const float4* qp = (const float4*)(Qg + boff + (size_t)(s0 + r) * D_DIM + d8 * 8);
        const float4* kp = (const float4*)(Kg + boff + (size_t)(s0 + r) * D_DIM + d8 * 8);
        const float4* vp = (const float4*)(Vg + boff + (size_t)(s0 + r) * D_DIM + d8 * 8);
        float4 q0 = qp[0], q1 = qp[1];
        float4 k0 = kp[0], k1 = kp[1];
        float4 v0 = vp[0], v1 = vp[1];
        bf16x8 qo, ko;
        qo[0] = (__bf16)(q0.x * SCALE); qo[1] = (__bf16)(q0.y * SCALE);
        qo[2] = (__bf16)(q0.z * SCALE); qo[3] = (__bf16)(q0.w * SCALE);
        qo[4] = (__bf16)(q1.x * SCALE); qo[5] = (__bf16)(q1.y * SCALE);
        qo[6] = (__bf16)(q1.z * SCALE); qo[7] = (__bf16)(q1.w * SCALE);
        ko[0] = (__bf16)k0.x; ko[1] = (__bf16)k0.y; ko[2] = (__bf16)k0.z; ko[3] = (__bf16)k0.w;
        ko[4] = (__bf16)k1.x; ko[5] = (__bf16)k1.y; ko[6] = (__bf16)k1.z; ko[7] = (__bf16)k1.w;
        *(bf16x8*)&Qbf[boff + (size_t)(s0 + r) * D_DIM + d8 * 8] = qo;
        *(bf16x8*)&Ktil[tbase + (size_t)((idx ^ (r & 7)) * 8)] = ko;
        const float vv[8] = {v0.x, v0.y, v0.z, v0.w, v1.x, v1.y, v1.z, v1.w};
        #pragma unroll
        for (int j = 0; j < 8; ++j) vt_l[d8 * 8 + j][r] = (__bf16)vv[j];
    }
    __syncthreads();

    #pragma unroll
    for (int rep = 0; rep < 2; ++rep) {
        const int idx = rep * 256 + tid;   // d*8 + k8
        const int d   = idx >> 3;
        bf16x8 vo = *(const bf16x8*)&vt_l[d][(idx & 7) * 8];
        *(bf16x8*)&Vtil[tbase + (size_t)((idx ^ (d & 7)) * 8)] = vo;
    }
}

// ---------------- main: 128-q supertile x 512-kv chunk; 4 waves x 32q (2 subtiles) ----------------
__global__ __launch_bounds__(256) void fattn_kernel(
    const __bf16* __restrict__ Qbf, const __bf16* __restrict__ Ktil,
    const __bf16* __restrict__ Vtil, __bf16* __restrict__ Part,
    float* __restrict__ Og)
{
    __shared__ __align__(16) __bf16 Ksm[2][4096];
    __shared__ __align__(16) __bf16 Vsm[2][4096];

    const int tid  = threadIdx.x;
    const int w    = tid >> 6;          // wave 0..3 (owns 32 q rows)
    const int lane = tid & 63;
    const int g    = lane >> 4;
    const int ln   = lane & 15;
    const bool oddg = (g & 1);

    // decode block -> (batch, T, chunk); heavy (large T) first
    const int bid   = blockIdx.x;          // 0..575
    const int batch = bid & 3;
    const int idx   = 143 - (bid >> 2);    // descending
    int q = 0;
    #pragma unroll
    for (int qq = 1; qq <= 7; ++qq)
        if (2 * qq * (qq + 1) <= idx) q = qq;
    const int rem   = idx - 2 * q * (q + 1);
    const int perq  = q + 1;               // nchunks for this T-group
    const int tsub  = rem / perq;
    const int T     = 4 * q + tsub;
    const int chunk = rem - tsub * perq;
    const int nc    = perq;

    const int q0b   = T << 7;              // block q base (128 rows)
    const int kv_lo = chunk << 9;
    const int kvcap = q0b + 128;
    const int kv_hi = (kv_lo + 512 < kvcap) ? (kv_lo + 512) : kvcap;
    const int nt    = (kv_hi - kv_lo + 63) >> 6;
    const bool finalc = (chunk == nc - 1);

    const int q0w  = q0b + (w << 5);       // wave q base (32 rows, 2 subtiles of 16)
    const int qmax = q0w + 31;

    const size_t boff = (size_t)batch * S_LEN * D_DIM;
    const size_t ktb0 = ((size_t)batch * NT64 + (kv_lo >> 6)) * 4096;

    // Q fragments for both subtiles (B-operand: n=ln -> q row, k = ds*32+g*8+i)
    bf16x8 qf[2][2];
    #pragma unroll
    for (int qt = 0; qt < 2; ++qt)
        #pragma unroll
        for (int ds = 0; ds < 2; ++ds)
            qf[qt][ds] = *(const bf16x8*)&Qbf[boff + (size_t)(q0w + qt * 16 + ln) * D_DIM + ds * 32 + g * 8];

    const f32x4 Z4 = {0.f, 0.f, 0.f, 0.f};
    f32x4 acco[2][4] = {{Z4, Z4, Z4, Z4}, {Z4, Z4, Z4, Z4}};
    float mrun[2] = {-1e30f, -1e30f}, lrun[2] = {0.f, 0.f};   // per-lane q-row = q0w+qt*16+ln

#define STAGE(BUF, IT_)                                                              \
    do {                                                                             \
        const __bf16* kb_ = Ktil + ktb0 + (size_t)(IT_) * 4096;                      \
        const __bf16* vb_ = Vtil + ktb0 + (size_t)(IT_) * 4096;                      \
        _Pragma("unroll")                                                            \
        for (int p = 0; p < 2; ++p) {                                                \
            __builtin_amdgcn_global_load_lds((gbl_u32p)(kb_ + (size_t)(p * 256 + tid) * 8), \
                (lds_u32p)&Ksm[BUF][(p * 256 + w * 64) * 8], 16, 0, 0);              \
            __builtin_amdgcn_global_load_lds((gbl_u32p)(vb_ + (size_t)(p * 256 + tid) * 8), \
                (lds_u32p)&Vsm[BUF][(p * 256 + w * 64) * 8], 16, 0, 0);              \
        }                                                                            \
    } while (0)

    STAGE(0, 0);
    asm volatile("s_waitcnt vmcnt(0)" ::: "memory");
    __syncthreads();

    for (int it = 0; it < nt; ++it) {
        const int kv0 = kv_lo + (it << 6);
        const int buf = it & 1;
        if (it + 1 < nt) STAGE(buf ^ 1, it + 1);

        if (!finalc || kv0 <= qmax) {
            const __bf16* Kb = Ksm[buf];
            const __bf16* Vb = Vsm[buf];

            // ---- K fragments once per tile, shared by both q-subtiles ----
            bf16x8 kf[4][2];
            #pragma unroll
            for (int ns = 0; ns < 4; ++ns) {
                const int row = ns * 16 + ln;
                kf[ns][0] = *(const bf16x8*)&Kb[(size_t)(((row * 8 + g)     ^ (row & 7)) * 8)];
                kf[ns][1] = *(const bf16x8*)&Kb[(size_t)(((row * 8 + 4 + g) ^ (row & 7)) * 8)];
            }
            // ---- V fragments once per tile, shared by both q-subtiles ----
            bf16x8 vf[4][2];
            #pragma unroll
            for (int nb = 0; nb < 4; ++nb) {
                const int vrow = nb * 16 + ln;
                vf[nb][0] = *(const bf16x8*)&Vb[(size_t)(((vrow * 8 + g)     ^ (vrow & 7)) * 8)];
                vf[nb][1] = *(const bf16x8*)&Vb[(size_t)(((vrow * 8 + 4 + g) ^ (vrow & 7)) * 8)];
            }

            #pragma unroll
            for (int qt = 0; qt < 2; ++qt) {
                if (finalc && kv0 > q0w + qt * 16 + 15) continue;   // subtile fully masked

                // ---- swapped QK^T: accs = S^T[kv][q]; lane: q=ln, kv=ns*16+g*4+i ----
                f32x4 accs[4];
                #pragma unroll
                for (int ns = 0; ns < 4; ++ns) {
                    accs[ns] = __builtin_amdgcn_mfma_f32_16x16x32_bf16(kf[ns][0], qf[qt][0], Z4, 0, 0, 0);
                    accs[ns] = __builtin_amdgcn_mfma_f32_16x16x32_bf16(kf[ns][1], qf[qt][1], accs[ns], 0, 0, 0);
                }

                // ---- causal mask (diagonal-overlapping tiles of the final chunk only) ----
                if (finalc && kv0 + 63 > q0w + qt * 16) {
                    const int qg = q0w + qt * 16 + ln;
                    #pragma unroll
                    for (int ns = 0; ns < 4; ++ns)
                        #pragma unroll
                        for (int i = 0; i < 4; ++i)
                            if (kv0 + ns * 16 + g * 4 + i > qg) accs[ns][i] = -1e30f;
                }

                // ---- defer-max online softmax (T13); verified shfl_xor reduce ----
                float mx = accs[0][0];
                #pragma unroll
                for (int ns = 0; ns < 4; ++ns)
                    #pragma unroll
                    for (int i = 0; i < 4; ++i) mx = fmaxf(mx, accs[ns][i]);
                mx = fmaxf(mx, __shfl_xor(mx, 16));
                mx = fmaxf(mx, __shfl_xor(mx, 32));
                if (!__all(mx <= mrun[qt] + 4.0f)) {
                    const float mnew  = fmaxf(mrun[qt], mx);
                    const float alpha = exp2f(mrun[qt] - mnew);
                    mrun[qt] = mnew;
                    lrun[qt] *= alpha;
                    float ar[4];
                    #pragma unroll
                    for (int i = 0; i < 4; ++i)
                        ar[i] = __shfl(alpha, (g << 4) + (g << 2) + i);
                    #pragma unroll
                    for (int nb = 0; nb < 4; ++nb)
                        #pragma unroll
                        for (int i = 0; i < 4; ++i) acco[qt][nb][i] *= ar[i];
                }
                float rs = 0.f;
                #pragma unroll
                for (int ns = 0; ns < 4; ++ns)
                    #pragma unroll
                    for (int i = 0; i < 4; ++i) {
                        accs[ns][i] = exp2f(accs[ns][i] - mrun[qt]);
                        rs += accs[ns][i];
                    }
                lrun[qt] += rs;   // g-partial; combined at epilogue

                // ---- P^T -> A-fragment transpose, fully in registers (verified wiring) ----
                uint_t cpk[4][2];
                #pragma unroll
                for (int ns = 0; ns < 4; ++ns)
                    #pragma unroll
                    for (int jp = 0; jp < 2; ++jp) {
                        float lo = accs[ns][2 * jp], hi = accs[ns][2 * jp + 1];
                        asm("v_cvt_pk_bf16_f32 %0, %1, %2" : "=v"(cpk[ns][jp]) : "v"(lo), "v"(hi));
                    }
                union { uint_t u[4]; bf16x8 v; } pfu[2];
                #pragma unroll
                for (int ks = 0; ks < 2; ++ks)
                    #pragma unroll
                    for (int jp = 0; jp < 2; ++jp) {
                        uint_t a = cpk[2 * ks][jp], b = cpk[2 * ks + 1][jp];
                        asm volatile("v_permlane32_swap_b32 %0, %1" : "+v"(a), "+v"(b));
                        const uint_t rax = (uint_t)__shfl_xor((int)a, 16);
                        const uint_t rbx = (uint_t)__shfl_xor((int)b, 16);
                        pfu[ks].u[jp]     = oddg ? rbx : a;
                        pfu[ks].u[2 + jp] = oddg ? b   : rax;
                    }

                // ---- PV : O += P @ V ----
                #pragma unroll
                for (int nb = 0; nb < 4; ++nb) {
                    acco[qt][nb] = __builtin_amdgcn_mfma_f32_16x16x32_bf16(pfu[0].v, vf[nb][0], acco[qt][nb], 0, 0, 0);
                    acco[qt][nb] = __builtin_amdgcn_mfma_f32_16x16x32_bf16(pfu[1].v, vf[nb][1], acco[qt][nb], 0, 0, 0);
                }
            }
        }

        asm volatile("s_waitcnt vmcnt(0)" ::: "memory");
        __syncthreads();
    }
#undef STAGE

    // ---- cross-g combine of deferred l-partials (verified shfl_xor) ----
    #pragma unroll
    for (int qt = 0; qt < 2; ++qt) {
        lrun[qt] += __shfl_xor(lrun[qt], 16);
        lrun[qt] += __shfl_xor(lrun[qt], 32);
    }

    if (nc == 1) {
        // single-chunk supertile: normalize and write output directly
        float* Ob = Og + boff;
        #pragma unroll
        for (int qt = 0; qt < 2; ++qt) {
            float lr[4];
            #pragma unroll
            for (int i = 0; i < 4; ++i)
                lr[i] = __shfl(lrun[qt], (g << 4) + (g << 2) + i);
            #pragma unroll
            for (int nb = 0; nb < 4; ++nb)
                #pragma unroll
                for (int i = 0; i < 4; ++i)
                    Ob[(size_t)(q0w + qt * 16 + g * 4 + i) * D_DIM + nb * 16 + ln] = acco[qt][nb][i] / lr[i];
        }
    } else {
        // partial: O bf16 [128][64] + m[128],l[128] f32
        const int slot = batch * IPB + 2 * q * (q + 1) - 4 + (T & 3) * (q + 1) + chunk;
        __bf16* Op = Part + (size_t)slot * PITEM;
        float* MLp = (float*)(Op + 8192);
        #pragma unroll
        for (int qt = 0; qt < 2; ++qt) {
            #pragma unroll
            for (int nb = 0; nb < 4; ++nb)
                #pragma unroll
                for (int i = 0; i < 4; ++i)
                    Op[(size_t)(w * 32 + qt * 16 + g * 4 + i) * 64 + nb * 16 + ln] = (__bf16)acco[qt][nb][i];
            if (lane < 16) {
                MLp[w * 32 + qt * 16 + lane]       = mrun[qt];
                MLp[128 + w * 32 + qt * 16 + lane] = lrun[qt];
            }
        }
    }
}

// ---------------- combine: element-parallel merge for multi-chunk supertiles (T >= 4) ----------------
// One thread per output element: 4 batches x 28 supertiles x 128 rows x 64 dims = 917504.
__global__ __launch_bounds__(256) void combine_kernel(
    const __bf16* __restrict__ Part, float* __restrict__ Og)
{
    const int idx = blockIdx.x * 256 + threadIdx.x;   // 0..917503
    const int d   = idx & 63;
    const int rr  = (idx >> 6) & 127;
    const int bt  = idx >> 13;            // 0..111 = batch*28 + (T-4)
    const int batch = bt / 28;
    const int T   = 4 + (bt - batch * 28);
    const int q   = T >> 2;
    const int nc  = q + 1;
    const int sbase = batch * IPB + 2 * q * (q + 1) - 4 + (T & 3) * (q + 1);

    // pass 1: row max over chunks (m values are L2-hot broadcasts)
    float M = -1e30f;
    for (int c = 0; c < nc; ++c)
        M = fmaxf(M, ((const float*)(Part + (size_t)(sbase + c) * PITEM + 8192))[rr]);

    // pass 2: weighted sum
    float val = 0.f, L = 0.f;
    for (int c = 0; c < nc; ++c) {
        const float* MLp = (const float*)(Part + (size_t)(sbase + c) * PITEM + 8192);
        const float al = exp2f(MLp[rr] - M);
        val += al * (float)Part[(size_t)(sbase + c) * PITEM + rr * 64 + d];
        L   += al * MLp[128 + rr];
    }
    Og[(size_t)batch * S_LEN * D_DIM + (size_t)((T << 7) + rr) * D_DIM + d] = val / L;
}

extern "C" void kernel_launch(void* const* d_in, const int* in_sizes, int n_in,
                              void* d_out, int out_size, void* d_ws, size_t ws_size,
                              hipStream_t stream) {
    const float* qf = (const float*)d_in[0];
    const float* kf = (const float*)d_in[1];
    const float* vf = (const float*)d_in[2];
    float* o = (float*)d_out;

    const size_t NELEM = (size_t)4 * S_LEN * D_DIM;   // 1M bf16 per buffer
    __bf16* Qbf  = (__bf16*)d_ws;          // 2 MB
    __bf16* Ktil = Qbf + NELEM;            // 2 MB (swizzled 64x64 tiles)
    __bf16* Vtil = Ktil + NELEM;           // 2 MB (transposed swizzled tiles)
    __bf16* Part = Vtil + NELEM;           // 560 * 17408 B = 9.75 MB

    hipLaunchKernelGGL(prep_kernel, dim3(256), dim3(256), 0, stream, qf, kf, vf, Qbf, Ktil, Vtil);
    // 576 blocks = 4 batches x 144 (supertile, chunk) items, heavy-first; 4 waves x 32 q
    hipLaunchKernelGGL(fattn_kernel, dim3(576), dim3(256), 0, stream, Qbf, Ktil, Vtil, Part, o);
    // element-parallel merge: 917504 elements / 256 = 3584 blocks
    hipLaunchKernelGGL(combine_kernel, dim3(3584), dim3(256), 0, stream, Part, o);
}

// Round 17
// 49.909 us; speedup vs baseline: 1.2221x; 1.2221x over previous
//
#include <hip/hip_runtime.h>
#include <hip/hip_bf16.h>

typedef __attribute__((ext_vector_type(4))) float  f32x4;
typedef __attribute__((ext_vector_type(8))) __bf16 bf16x8;
typedef unsigned int uint_t;

#define S_LEN  4096
#define D_DIM  64
#define NT64   64       /* 64-seq tiles per batch */
#define PITEM  8704     /* bf16 units per partial: O[128][64] bf16 + m[128],l[128] f32 */
#define IPB    140      /* multi-chunk partial items per batch */

typedef __attribute__((address_space(3))) uint_t*       lds_u32p;
typedef const __attribute__((address_space(1))) uint_t* gbl_u32p;

// ---------------- pre-pass: Q bf16 (scaled) row-major; K,V -> swizzled 64x64 tiles ----------------
// Tile chunk layout (16B units): chunk c_lin = row*8 + col16 stored at c_lin ^ (row&7).
// V tiles are transposed (rows = d, cols = kv).
__global__ __launch_bounds__(256) void prep_kernel(
    const float* __restrict__ Qg, const float* __restrict__ Kg,
    const float* __restrict__ Vg,
    __bf16* __restrict__ Qbf, __bf16* __restrict__ Ktil, __bf16* __restrict__ Vtil)
{
    __shared__ __bf16 vt_l[64][72];

    const float SCALE = 0.125f * 1.44269504088896340736f; // 1/sqrt(64) * log2(e)
    const int tid   = threadIdx.x;
    const int bid   = blockIdx.x;
    const int batch = bid >> 6;
    const int ti    = bid & 63;
    const int s0    = ti << 6;
    const size_t boff  = (size_t)batch * S_LEN * D_DIM;
    const size_t tbase = ((size_t)batch * NT64 + ti) * 4096;

    #pragma unroll
    for (int rep = 0; rep < 2; ++rep) {
        const int idx = rep * 256 + tid;   // 0..511 : 16B chunk id (r*8 + d8)
        const int r   = idx >> 3;
        const int d8  = idx & 7;
        const float4* qp = (const float4*)(Qg + boff + (size_t)(s0 + r) * D_DIM + d8 * 8);
        const float4* kp = (const float4*)(Kg + boff + (size_t)(s0 + r) * D_DIM + d8 * 8);
        const float4* vp = (const float4*)(Vg + boff + (size_t)(s0 + r) * D_DIM + d8 * 8);
        float4 q0 = qp[0], q1 = qp[1];
        float4 k0 = kp[0], k1 = kp[1];
        float4 v0 = vp[0], v1 = vp[1];
        bf16x8 qo, ko;
        qo[0] = (__bf16)(q0.x * SCALE); qo[1] = (__bf16)(q0.y * SCALE);
        qo[2] = (__bf16)(q0.z * SCALE); qo[3] = (__bf16)(q0.w * SCALE);
        qo[4] = (__bf16)(q1.x * SCALE); qo[5] = (__bf16)(q1.y * SCALE);
        qo[6] = (__bf16)(q1.z * SCALE); qo[7] = (__bf16)(q1.w * SCALE);
        ko[0] = (__bf16)k0.x; ko[1] = (__bf16)k0.y; ko[2] = (__bf16)k0.z; ko[3] = (__bf16)k0.w;
        ko[4] = (__bf16)k1.x; ko[5] = (__bf16)k1.y; ko[6] = (__bf16)k1.z; ko[7] = (__bf16)k1.w;
        *(bf16x8*)&Qbf[boff + (size_t)(s0 + r) * D_DIM + d8 * 8] = qo;
        *(bf16x8*)&Ktil[tbase + (size_t)((idx ^ (r & 7)) * 8)] = ko;
        const float vv[8] = {v0.x, v0.y, v0.z, v0.w, v1.x, v1.y, v1.z, v1.w};
        #pragma unroll
        for (int j = 0; j < 8; ++j) vt_l[d8 * 8 + j][r] = (__bf16)vv[j];
    }
    __syncthreads();

    #pragma unroll
    for (int rep = 0; rep < 2; ++rep) {
        const int idx = rep * 256 + tid;   // d*8 + k8
        const int d   = idx >> 3;
        bf16x8 vo = *(const bf16x8*)&vt_l[d][(idx & 7) * 8];
        *(bf16x8*)&Vtil[tbase + (size_t)((idx ^ (d & 7)) * 8)] = vo;
    }
}

// ---------------- main: 128-row Q-supertile x 512-kv chunk; LDS-shared K/V ----------------
__global__ __launch_bounds__(512, 4) void fattn_kernel(
    const __bf16* __restrict__ Qbf, const __bf16* __restrict__ Ktil,
    const __bf16* __restrict__ Vtil, __bf16* __restrict__ Part,
    float* __restrict__ Og)
{
    __shared__ __align__(16) __bf16 Ksm[2][4096];
    __shared__ __align__(16) __bf16 Vsm[2][4096];

    const int tid  = threadIdx.x;
    const int w    = tid >> 6;
    const int lane = tid & 63;
    const int g    = lane >> 4;
    const int ln   = lane & 15;
    const bool oddg = (g & 1);

    // decode block -> (batch, T, chunk); heavy (large T) first
    const int bid   = blockIdx.x;          // 0..575
    const int batch = bid & 3;
    const int idx   = 143 - (bid >> 2);    // descending
    int q = 0;
    #pragma unroll
    for (int qq = 1; qq <= 7; ++qq)
        if (2 * qq * (qq + 1) <= idx) q = qq;
    const int rem   = idx - 2 * q * (q + 1);
    const int perq  = q + 1;               // nchunks for this T-group
    const int tsub  = rem / perq;
    const int T     = 4 * q + tsub;
    const int chunk = rem - tsub * perq;
    const int nc    = perq;

    const int q0b   = T << 7;              // block q base (128 rows)
    const int kv_lo = chunk << 9;
    const int kvcap = q0b + 128;
    const int kv_hi = (kv_lo + 512 < kvcap) ? (kv_lo + 512) : kvcap;
    const int nt    = (kv_hi - kv_lo + 63) >> 6;
    const bool finalc = (chunk == nc - 1);

    const int q0w  = q0b + (w << 4);       // wave q base
    const int qmax = q0w + 15;

    const size_t boff = (size_t)batch * S_LEN * D_DIM;
    const size_t ktb0 = ((size_t)batch * NT64 + (kv_lo >> 6)) * 4096;

    // Q fragments (B-operand: n=ln -> q row, k = ds*32+g*8+i)
    bf16x8 qf0 = *(const bf16x8*)&Qbf[boff + (size_t)(q0w + ln) * D_DIM + g * 8];
    bf16x8 qf1 = *(const bf16x8*)&Qbf[boff + (size_t)(q0w + ln) * D_DIM + 32 + g * 8];

    const f32x4 Z4 = {0.f, 0.f, 0.f, 0.f};
    f32x4 acco[4] = {Z4, Z4, Z4, Z4};
    float mrun = -1e30f, lrun = 0.f;       // per-lane: q-row = q0w + ln (l g-partial)

#define STAGE(BUF, IT_)                                                              \
    do {                                                                             \
        const __bf16* ks_ = Ktil + ktb0 + (size_t)(IT_) * 4096 + (w * 64 + lane) * 8; \
        const __bf16* vs_ = Vtil + ktb0 + (size_t)(IT_) * 4096 + (w * 64 + lane) * 8; \
        __builtin_amdgcn_global_load_lds((gbl_u32p)ks_, (lds_u32p)&Ksm[BUF][w * 512], 16, 0, 0); \
        __builtin_amdgcn_global_load_lds((gbl_u32p)vs_, (lds_u32p)&Vsm[BUF][w * 512], 16, 0, 0); \
    } while (0)

    STAGE(0, 0);
    asm volatile("s_waitcnt vmcnt(0)" ::: "memory");
    __syncthreads();

    for (int it = 0; it < nt; ++it) {
        const int kv0 = kv_lo + (it << 6);
        const int buf = it & 1;
        if (it + 1 < nt) STAGE(buf ^ 1, it + 1);

        if (!finalc || kv0 <= qmax) {
            const __bf16* Kb = Ksm[buf];
            const __bf16* Vb = Vsm[buf];

            // swapped QK^T: accs = S^T[kv][q]; lane holds q=ln, kv = ns*16+g*4+i
            f32x4 accs[4];
            #pragma unroll
            for (int ns = 0; ns < 4; ++ns) {
                const int row = ns * 16 + ln;
                bf16x8 kf0 = *(const bf16x8*)&Kb[(size_t)(((row * 8 + g)     ^ (row & 7)) * 8)];
                bf16x8 kf1 = *(const bf16x8*)&Kb[(size_t)(((row * 8 + 4 + g) ^ (row & 7)) * 8)];
                accs[ns] = __builtin_amdgcn_mfma_f32_16x16x32_bf16(kf0, qf0, Z4, 0, 0, 0);
                accs[ns] = __builtin_amdgcn_mfma_f32_16x16x32_bf16(kf1, qf1, accs[ns], 0, 0, 0);
            }

            // causal mask (diagonal-overlapping tiles of the final chunk only)
            if (finalc && kv0 + 63 > q0w) {
                const int qg = q0w + ln;
                #pragma unroll
                for (int ns = 0; ns < 4; ++ns)
                    #pragma unroll
                    for (int i = 0; i < 4; ++i)
                        if (kv0 + ns * 16 + g * 4 + i > qg) accs[ns][i] = -1e30f;
            }

            // defer-max online softmax (T13)
            float mx = accs[0][0];
            #pragma unroll
            for (int ns = 0; ns < 4; ++ns)
                #pragma unroll
                for (int i = 0; i < 4; ++i) mx = fmaxf(mx, accs[ns][i]);
            if (!__all(mx <= mrun + 4.0f)) {
                mx = fmaxf(mx, __shfl_xor(mx, 16));
                mx = fmaxf(mx, __shfl_xor(mx, 32));
                const float mnew  = fmaxf(mrun, mx);
                const float alpha = exp2f(mrun - mnew);
                mrun = mnew;
                lrun *= alpha;
                float ar[4];
                #pragma unroll
                for (int i = 0; i < 4; ++i)
                    ar[i] = __shfl(alpha, (g << 4) + (g << 2) + i);
                #pragma unroll
                for (int nb = 0; nb < 4; ++nb)
                    #pragma unroll
                    for (int i = 0; i < 4; ++i) acco[nb][i] *= ar[i];
            }
            float rs = 0.f;
            #pragma unroll
            for (int ns = 0; ns < 4; ++ns)
                #pragma unroll
                for (int i = 0; i < 4; ++i) {
                    accs[ns][i] = exp2f(accs[ns][i] - mrun);
                    rs += accs[ns][i];
                }
            lrun += rs;   // g-partial

            // P^T -> A-fragment transpose, fully in registers
            uint_t cpk[4][2];
            #pragma unroll
            for (int ns = 0; ns < 4; ++ns)
                #pragma unroll
                for (int jp = 0; jp < 2; ++jp) {
                    float lo = accs[ns][2 * jp], hi = accs[ns][2 * jp + 1];
                    asm("v_cvt_pk_bf16_f32 %0, %1, %2" : "=v"(cpk[ns][jp]) : "v"(lo), "v"(hi));
                }
            union { uint_t u[4]; bf16x8 v; } pfu[2];
            #pragma unroll
            for (int ks = 0; ks < 2; ++ks)
                #pragma unroll
                for (int jp = 0; jp < 2; ++jp) {
                    uint_t a = cpk[2 * ks][jp], b = cpk[2 * ks + 1][jp];
                    asm volatile("v_permlane32_swap_b32 %0, %1" : "+v"(a), "+v"(b));
                    const uint_t rax = (uint_t)__shfl_xor((int)a, 16);
                    const uint_t rbx = (uint_t)__shfl_xor((int)b, 16);
                    pfu[ks].u[jp]     = oddg ? rbx : a;
                    pfu[ks].u[2 + jp] = oddg ? b   : rax;
                }

            // PV : O += P @ V   (V fragments from swizzled LDS)
            #pragma unroll
            for (int nb = 0; nb < 4; ++nb) {
                const int vrow = nb * 16 + ln;
                bf16x8 vf0 = *(const bf16x8*)&Vb[(size_t)(((vrow * 8 + g)     ^ (vrow & 7)) * 8)];
                bf16x8 vf1 = *(const bf16x8*)&Vb[(size_t)(((vrow * 8 + 4 + g) ^ (vrow & 7)) * 8)];
                acco[nb] = __builtin_amdgcn_mfma_f32_16x16x32_bf16(pfu[0].v, vf0, acco[nb], 0, 0, 0);
                acco[nb] = __builtin_amdgcn_mfma_f32_16x16x32_bf16(pfu[1].v, vf1, acco[nb], 0, 0, 0);
            }
        }

        asm volatile("s_waitcnt vmcnt(0)" ::: "memory");
        __syncthreads();
    }
#undef STAGE

    // ---- cross-g combine of deferred l-partials ----
    lrun += __shfl_xor(lrun, 16);
    lrun += __shfl_xor(lrun, 32);

    if (nc == 1) {
        // single-chunk supertile: normalize and write output directly
        float lr[4];
        #pragma unroll
        for (int i = 0; i < 4; ++i)
            lr[i] = __shfl(lrun, (g << 4) + (g << 2) + i);
        float* Ob = Og + boff;
        #pragma unroll
        for (int nb = 0; nb < 4; ++nb)
            #pragma unroll
            for (int i = 0; i < 4; ++i)
                Ob[(size_t)(q0w + g * 4 + i) * D_DIM + nb * 16 + ln] = acco[nb][i] / lr[i];
    } else {
        // partial: O bf16 [128][64] + m[128],l[128] f32
        const int slot = batch * IPB + 2 * q * (q + 1) - 4 + (T & 3) * (q + 1) + chunk;
        __bf16* Op = Part + (size_t)slot * PITEM;
        #pragma unroll
        for (int nb = 0; nb < 4; ++nb)
            #pragma unroll
            for (int i = 0; i < 4; ++i)
                Op[(size_t)(w * 16 + g * 4 + i) * 64 + nb * 16 + ln] = (__bf16)acco[nb][i];
        float* MLp = (float*)(Op + 8192);
        if (lane < 16) {
            MLp[w * 16 + ln]       = mrun;
            MLp[128 + w * 16 + ln] = lrun;
        }
    }
}

// ---------------- combine: element-parallel merge for multi-chunk supertiles (T >= 4) ----------------
// One thread per output element: 4 batches x 28 supertiles x 128 rows x 64 dims = 917504.
__global__ __launch_bounds__(256) void combine_kernel(
    const __bf16* __restrict__ Part, float* __restrict__ Og)
{
    const int idx = blockIdx.x * 256 + threadIdx.x;   // 0..917503
    const int d   = idx & 63;
    const int rr  = (idx >> 6) & 127;
    const int bt  = idx >> 13;            // 0..111 = batch*28 + (T-4)
    const int batch = bt / 28;
    const int T   = 4 + (bt - batch * 28);
    const int q   = T >> 2;
    const int nc  = q + 1;
    const int sbase = batch * IPB + 2 * q * (q + 1) - 4 + (T & 3) * (q + 1);

    // pass 1: row max over chunks (m values are L2-hot broadcasts)
    float M = -1e30f;
    for (int c = 0; c < nc; ++c)
        M = fmaxf(M, ((const float*)(Part + (size_t)(sbase + c) * PITEM + 8192))[rr]);

    // pass 2: weighted sum
    float val = 0.f, L = 0.f;
    for (int c = 0; c < nc; ++c) {
        const float* MLp = (const float*)(Part + (size_t)(sbase + c) * PITEM + 8192);
        const float al = exp2f(MLp[rr] - M);
        val += al * (float)Part[(size_t)(sbase + c) * PITEM + rr * 64 + d];
        L   += al * MLp[128 + rr];
    }
    Og[(size_t)batch * S_LEN * D_DIM + (size_t)((T << 7) + rr) * D_DIM + d] = val / L;
}

extern "C" void kernel_launch(void* const* d_in, const int* in_sizes, int n_in,
                              void* d_out, int out_size, void* d_ws, size_t ws_size,
                              hipStream_t stream) {
    const float* qf = (const float*)d_in[0];
    const float* kf = (const float*)d_in[1];
    const float* vf = (const float*)d_in[2];
    float* o = (float*)d_out;

    const size_t NELEM = (size_t)4 * S_LEN * D_DIM;   // 1M bf16 per buffer
    __bf16* Qbf  = (__bf16*)d_ws;          // 2 MB
    __bf16* Ktil = Qbf + NELEM;            // 2 MB (swizzled 64x64 tiles)
    __bf16* Vtil = Ktil + NELEM;           // 2 MB (transposed swizzled tiles)
    __bf16* Part = Vtil + NELEM;           // 560 * 17408 B = 9.75 MB

    hipLaunchKernelGGL(prep_kernel, dim3(256), dim3(256), 0, stream, qf, kf, vf, Qbf, Ktil, Vtil);
    // 576 blocks = 4 batches x 144 (supertile, chunk) items, heavy-first
    hipLaunchKernelGGL(fattn_kernel, dim3(576), dim3(512), 0, stream, Qbf, Ktil, Vtil, Part, o);
    // element-parallel merge: 917504 elements / 256 = 3584 blocks
    hipLaunchKernelGGL(combine_kernel, dim3(3584), dim3(256), 0, stream, Part, o);
}